// Round 6
// baseline (173.338 us; speedup 1.0000x reference)
//
#include <hip/hip_runtime.h>
#include <stdint.h>
#include <stddef.h>

typedef __attribute__((ext_vector_type(4))) int i32x4;

#define AS1q __attribute__((address_space(1)))
#define AS3q __attribute__((address_space(3)))

__device__ __forceinline__ void gload16(const void* g, void* l) {
    __builtin_amdgcn_global_load_lds((const AS1q uint32_t*)g, (AS3q uint32_t*)l, 16, 0, 0);
}

#define VMCNT(n)  asm volatile("s_waitcnt vmcnt(" #n ")" ::: "memory")
#define BARRIER() asm volatile("s_barrier" ::: "memory")

#define EPSQ 1e-8f

// ---------------- Quant: one block per token (K == 4096 fast path) ----------------
__global__ __launch_bounds__(256) void quant4096(
    const float* __restrict__ x, int8_t* __restrict__ xq, float* __restrict__ sx)
{
    constexpr int K = 4096;
    const int t = blockIdx.x;
    const int tid = threadIdx.x;
    const float4* row4 = (const float4*)(x + (size_t)t * K);
    float4 v0 = row4[0 * 256 + tid];
    float4 v1 = row4[1 * 256 + tid];
    float4 v2 = row4[2 * 256 + tid];
    float4 v3 = row4[3 * 256 + tid];
    auto mx4 = [](float4 a) {
        return fmaxf(fmaxf(fabsf(a.x), fabsf(a.y)), fmaxf(fabsf(a.z), fabsf(a.w)));
    };
    float am = fmaxf(fmaxf(mx4(v0), mx4(v1)), fmaxf(mx4(v2), mx4(v3)));
    #pragma unroll
    for (int off = 32; off > 0; off >>= 1)
        am = fmaxf(am, __shfl_xor(am, off, 64));
    __shared__ float wmax[4];
    if ((tid & 63) == 0) wmax[tid >> 6] = am;
    __syncthreads();
    float r = fmaxf(fmaxf(wmax[0], wmax[1]), fmaxf(wmax[2], wmax[3]));
    const float s = fmaxf(r, EPSQ) / 127.0f;   // true fdiv: match reference
    if (tid == 0) sx[t] = s;
    int* qrow = (int*)(xq + (size_t)t * K);
    auto pack = [&](float4 a) {
        int q0 = (int)fminf(fmaxf(rintf(a.x / s), -128.f), 127.f);
        int q1 = (int)fminf(fmaxf(rintf(a.y / s), -128.f), 127.f);
        int q2 = (int)fminf(fmaxf(rintf(a.z / s), -128.f), 127.f);
        int q3 = (int)fminf(fmaxf(rintf(a.w / s), -128.f), 127.f);
        return (q0 & 255) | ((q1 & 255) << 8) | ((q2 & 255) << 16) | ((q3 & 255) << 24);
    };
    qrow[0 * 256 + tid] = pack(v0);
    qrow[1 * 256 + tid] = pack(v1);
    qrow[2 * 256 + tid] = pack(v2);
    qrow[3 * 256 + tid] = pack(v3);
}

// generic fallback (any K multiple of 4)
__global__ __launch_bounds__(256) void quant_any(
    const float* __restrict__ x, int8_t* __restrict__ xq, float* __restrict__ sx, int K)
{
    const int t = blockIdx.x;
    const int tid = threadIdx.x;
    const float* row = x + (size_t)t * K;
    float am = 0.f;
    for (int i = tid; i < K; i += 256) am = fmaxf(am, fabsf(row[i]));
    #pragma unroll
    for (int off = 32; off > 0; off >>= 1)
        am = fmaxf(am, __shfl_xor(am, off, 64));
    __shared__ float wmax[4];
    if ((tid & 63) == 0) wmax[tid >> 6] = am;
    __syncthreads();
    float r = fmaxf(fmaxf(wmax[0], wmax[1]), fmaxf(wmax[2], wmax[3]));
    const float s = fmaxf(r, EPSQ) / 127.0f;
    if (tid == 0) sx[t] = s;
    int8_t* qrow = xq + (size_t)t * K;
    for (int i = tid; i < K; i += 256) {
        float q = fminf(fmaxf(rintf(row[i] / s), -128.f), 127.f);
        qrow[i] = (int8_t)(int)q;
    }
}

// ---------------- Pack: weight arrives as int32 (harness ABI), repack to int8 ----------------
__global__ __launch_bounds__(256) void pack_w(
    const int* __restrict__ w32, int8_t* __restrict__ w8, long long n4)
{
    const long long stride = (long long)gridDim.x * 256;
    for (long long i = (long long)blockIdx.x * 256 + threadIdx.x; i < n4; i += stride) {
        int4 v = ((const int4*)w32)[i];
        ((int*)w8)[i] = (v.x & 255) | ((v.y & 255) << 8) | ((v.z & 255) << 16) | ((v.w & 255) << 24);
    }
}

// ---------------- int8 GEMM, 2-phase split, big wave tile ----------------
// BM=256, BN=128, BK=64B. 4 waves (2m x 2n), wave tile 128x64 = 8x4 frags of
// 16x16x64 -> 32 MFMA/K-tile/wave, 12 ds_reads/wave (LDS:MFMA ~0.66, m201
// proportion). 2 phases of 16 MFMA. Block=256 thr, LDS 3x24KB=72KB ->
// 2 blocks/CU (8 waves = 2/SIMD), phases stagger across blocks.
// Grid (M/256)*(N/128) = 768.
// LDS: two 64B logical rows per 128B phys row, XOR swizzle x ^= (R&7)<<4
// (R2 counter-verified conflict-free); linear dest via global_load_lds +
// inverse-swizzled per-lane global src (rule #21).
// vmcnt ledger: 6 loads/tile/thread, prefetch distance 2 (3 buffers).
// Prologue stages T0,T1 (12 out). Boundary kt: vmcnt(6) retires tile kt's 6,
// keeps kt+1's 6 in flight; barrier publishes. Stage kt+2 inside phases.
__global__ __launch_bounds__(256) void gemm_i8(
    const int8_t* __restrict__ xq, const int8_t* __restrict__ w,
    const float* __restrict__ sx, const float* __restrict__ scale,
    const float* __restrict__ bias, float* __restrict__ out,
    int M, int N, int K)
{
    __shared__ __align__(16) uint8_t lds[3][24576];   // [buf][A 16KB | B 8KB]
    const int tid  = threadIdx.x;
    const int lane = tid & 63;
    const int wv   = tid >> 6;
    const int wr   = wv >> 1, wc = wv & 1;

    // bijective XCD swizzle (m204); nwg=768 -> %8==0
    const int nwg = gridDim.x;
    const int q8 = nwg >> 3, r8 = nwg & 7;
    const int xcd = blockIdx.x & 7, idx8 = blockIdx.x >> 3;
    const int wg = (xcd < r8 ? xcd * (q8 + 1) : r8 * (q8 + 1) + (xcd - r8) * q8) + idx8;

    const int NBM = M >> 8;
    const int bm = wg % NBM;
    const int bn = wg / NBM;       // col-panel-major: B panel (512KB) L2-resident
    const int brow = bm << 8, bcol = bn << 7;

    // staging sources (inverse-swizzled): chunk li covers phys bytes li*16..+15;
    // phys row R=li>>3 (128B), x=(li&7)<<4; logical r=(R<<1)|((x^swz)>>6), c=(x^swz)&63.
    const int8_t* srcA[4];
    const int8_t* srcB[2];
    #pragma unroll
    for (int e = 0; e < 4; ++e) {
        int li = e * 256 + tid;
        int R  = li >> 3;
        int x  = ((li & 7) << 4) ^ ((R & 7) << 4);
        srcA[e] = xq + (size_t)(brow + ((R << 1) | (x >> 6))) * K + (x & 63);
    }
    #pragma unroll
    for (int e = 0; e < 2; ++e) {
        int li = e * 256 + tid;
        int R  = li >> 3;
        int x  = ((li & 7) << 4) ^ ((R & 7) << 4);
        srcB[e] = w + (size_t)(bcol + ((R << 1) | (x >> 6))) * K + (x & 63);
    }

    // fragment LDS byte offsets (verified R2 formula)
    int offA[8], offB[4];
    #pragma unroll
    for (int m = 0; m < 8; ++m) {
        int r  = wr * 128 + m * 16 + (lane & 15);
        int R  = r >> 1;
        int x  = (((r & 1) << 6) | (lane & 48)) ^ ((R & 7) << 4);
        offA[m] = R * 128 + x;
    }
    #pragma unroll
    for (int n = 0; n < 4; ++n) {
        int r  = wc * 64 + n * 16 + (lane & 15);
        int R  = r >> 1;
        int x  = (((r & 1) << 6) | (lane & 48)) ^ ((R & 7) << 4);
        offB[n] = 16384 + R * 128 + x;
    }

    i32x4 acc[8][4] = {};

    auto stageA = [&](int buf, int kt) {
        const size_t ko = (size_t)kt << 6;
        #pragma unroll
        for (int e = 0; e < 4; ++e)
            gload16(srcA[e] + ko, &lds[buf][e * 4096 + wv * 1024]);
    };
    auto stageB = [&](int buf, int kt) {
        const size_t ko = (size_t)kt << 6;
        #pragma unroll
        for (int e = 0; e < 2; ++e)
            gload16(srcB[e] + ko, &lds[buf][16384 + e * 4096 + wv * 1024]);
    };

    const int NT = K >> 6;     // 64
    stageA(0, 0); stageB(0, 0);
    if (NT > 1) { stageA(1, 1); stageB(1, 1); }
    int cur = 0;
    for (int kt = 0; kt < NT; ++kt) {
        if (kt < NT - 1) { VMCNT(6); } else { VMCNT(0); }
        BARRIER();                               // tile kt visible; buf[(cur+2)%3] free
        const uint8_t* buf = lds[cur];
        const bool pf = (kt + 2 < NT);
        int nb = cur + 2; if (nb >= 3) nb -= 3;

        i32x4 av0[4], av1[4], bv[4];
        // ---- phase 0: read av(m0..3)+bv, stage A(kt+2), MFMA m0..3 ----
        #pragma unroll
        for (int m = 0; m < 4; ++m) av0[m] = *(const i32x4*)(buf + offA[m]);
        #pragma unroll
        for (int n = 0; n < 4; ++n) bv[n] = *(const i32x4*)(buf + offB[n]);
        if (pf) stageA(nb, kt + 2);
        BARRIER();
        __builtin_amdgcn_s_setprio(1);
        #pragma unroll
        for (int m = 0; m < 4; ++m)
            #pragma unroll
            for (int n = 0; n < 4; ++n)
                acc[m][n] = __builtin_amdgcn_mfma_i32_16x16x64_i8(av0[m], bv[n], acc[m][n], 0, 0, 0);
        __builtin_amdgcn_s_setprio(0);
        BARRIER();
        // ---- phase 1: read av(m4..7), stage B(kt+2), MFMA m4..7 ----
        #pragma unroll
        for (int m = 0; m < 4; ++m) av1[m] = *(const i32x4*)(buf + offA[4 + m]);
        if (pf) stageB(nb, kt + 2);
        BARRIER();
        __builtin_amdgcn_s_setprio(1);
        #pragma unroll
        for (int m = 0; m < 4; ++m)
            #pragma unroll
            for (int n = 0; n < 4; ++n)
                acc[4 + m][n] = __builtin_amdgcn_mfma_i32_16x16x64_i8(av1[m], bv[n], acc[4 + m][n], 0, 0, 0);
        __builtin_amdgcn_s_setprio(0);
        if (++cur >= 3) cur = 0;
    }

    // epilogue: out = acc * sx[row] * scale[col] + bias[col]
    const int orow = brow + wr * 128;
    const int ocol = bcol + wc * 64;
    float sxv[8][4];
    #pragma unroll
    for (int m = 0; m < 8; ++m)
        #pragma unroll
        for (int j = 0; j < 4; ++j)
            sxv[m][j] = sx[orow + m * 16 + ((lane >> 4) << 2) + j];
    #pragma unroll
    for (int n = 0; n < 4; ++n) {
        const int col = ocol + n * 16 + (lane & 15);
        const float sc = scale[col];
        const float bi = bias[col];
        #pragma unroll
        for (int m = 0; m < 8; ++m) {
            const int rb = orow + m * 16 + ((lane >> 4) << 2);
            #pragma unroll
            for (int j = 0; j < 4; ++j)
                out[(size_t)(rb + j) * N + col] = (float)acc[m][n][j] * sxv[m][j] * sc + bi;
        }
    }
}

extern "C" void kernel_launch(void* const* d_in, const int* in_sizes, int n_in,
                              void* d_out, int out_size, void* d_ws, size_t ws_size,
                              hipStream_t stream) {
    const float* x     = (const float*)d_in[0];
    const int*   w32   = (const int*)d_in[1];     // int8 weight arrives as int32 (harness ABI)
    const float* scale = (const float*)d_in[2];
    const float* bias  = (const float*)d_in[3];
    float* out = (float*)d_out;

    const int N = in_sizes[2];           // 6144
    const int K = in_sizes[1] / N;       // 4096
    const int M = in_sizes[0] / K;       // 4096

    // ws layout: xq [M*K int8] | wq [N*K int8] | sx [M f32]
    int8_t* xqbuf = (int8_t*)d_ws;
    int8_t* wqbuf = (int8_t*)d_ws + (size_t)M * K;
    float*  sxbuf = (float*)((uint8_t*)d_ws + (size_t)M * K + (size_t)N * K);

    if (K == 4096)
        quant4096<<<M, 256, 0, stream>>>(x, xqbuf, sxbuf);
    else
        quant_any<<<M, 256, 0, stream>>>(x, xqbuf, sxbuf, K);

    pack_w<<<2048, 256, 0, stream>>>(w32, wqbuf, (long long)N * K / 4);

    const int nwg = (M / 256) * (N / 128);   // 16*48 = 768
    gemm_i8<<<nwg, 256, 0, stream>>>(xqbuf, wqbuf, sxbuf, scale, bias, out, M, N, K);
}

// Round 7
// 160.992 us; speedup vs baseline: 1.0767x; 1.0767x over previous
//
#include <hip/hip_runtime.h>
#include <stdint.h>
#include <stddef.h>

typedef __attribute__((ext_vector_type(4))) int i32x4;

#define AS1q __attribute__((address_space(1)))
#define AS3q __attribute__((address_space(3)))

__device__ __forceinline__ void gload16(const void* g, void* l) {
    __builtin_amdgcn_global_load_lds((const AS1q uint32_t*)g, (AS3q uint32_t*)l, 16, 0, 0);
}

#define VMCNT(n)  asm volatile("s_waitcnt vmcnt(" #n ")" ::: "memory")
#define BARRIER() asm volatile("s_barrier" ::: "memory")

#define EPSQ 1e-8f

// ---------------- Quant: one block per token (K == 4096 fast path) ----------------
__global__ __launch_bounds__(256) void quant4096(
    const float* __restrict__ x, int8_t* __restrict__ xq, float* __restrict__ sx)
{
    constexpr int K = 4096;
    const int t = blockIdx.x;
    const int tid = threadIdx.x;
    const float4* row4 = (const float4*)(x + (size_t)t * K);
    float4 v0 = row4[0 * 256 + tid];
    float4 v1 = row4[1 * 256 + tid];
    float4 v2 = row4[2 * 256 + tid];
    float4 v3 = row4[3 * 256 + tid];
    auto mx4 = [](float4 a) {
        return fmaxf(fmaxf(fabsf(a.x), fabsf(a.y)), fmaxf(fabsf(a.z), fabsf(a.w)));
    };
    float am = fmaxf(fmaxf(mx4(v0), mx4(v1)), fmaxf(mx4(v2), mx4(v3)));
    #pragma unroll
    for (int off = 32; off > 0; off >>= 1)
        am = fmaxf(am, __shfl_xor(am, off, 64));
    __shared__ float wmax[4];
    if ((tid & 63) == 0) wmax[tid >> 6] = am;
    __syncthreads();
    float r = fmaxf(fmaxf(wmax[0], wmax[1]), fmaxf(wmax[2], wmax[3]));
    const float s = fmaxf(r, EPSQ) / 127.0f;   // true fdiv: match reference
    if (tid == 0) sx[t] = s;
    int* qrow = (int*)(xq + (size_t)t * K);
    auto pack = [&](float4 a) {
        int q0 = (int)fminf(fmaxf(rintf(a.x / s), -128.f), 127.f);
        int q1 = (int)fminf(fmaxf(rintf(a.y / s), -128.f), 127.f);
        int q2 = (int)fminf(fmaxf(rintf(a.z / s), -128.f), 127.f);
        int q3 = (int)fminf(fmaxf(rintf(a.w / s), -128.f), 127.f);
        return (q0 & 255) | ((q1 & 255) << 8) | ((q2 & 255) << 16) | ((q3 & 255) << 24);
    };
    qrow[0 * 256 + tid] = pack(v0);
    qrow[1 * 256 + tid] = pack(v1);
    qrow[2 * 256 + tid] = pack(v2);
    qrow[3 * 256 + tid] = pack(v3);
}

// generic fallback (any K multiple of 4)
__global__ __launch_bounds__(256) void quant_any(
    const float* __restrict__ x, int8_t* __restrict__ xq, float* __restrict__ sx, int K)
{
    const int t = blockIdx.x;
    const int tid = threadIdx.x;
    const float* row = x + (size_t)t * K;
    float am = 0.f;
    for (int i = tid; i < K; i += 256) am = fmaxf(am, fabsf(row[i]));
    #pragma unroll
    for (int off = 32; off > 0; off >>= 1)
        am = fmaxf(am, __shfl_xor(am, off, 64));
    __shared__ float wmax[4];
    if ((tid & 63) == 0) wmax[tid >> 6] = am;
    __syncthreads();
    float r = fmaxf(fmaxf(wmax[0], wmax[1]), fmaxf(wmax[2], wmax[3]));
    const float s = fmaxf(r, EPSQ) / 127.0f;
    if (tid == 0) sx[t] = s;
    int8_t* qrow = xq + (size_t)t * K;
    for (int i = tid; i < K; i += 256) {
        float q = fminf(fmaxf(rintf(row[i] / s), -128.f), 127.f);
        qrow[i] = (int8_t)(int)q;
    }
}

// ---------------- Pack: weight arrives as int32 (harness ABI), repack to int8 ----------------
__global__ __launch_bounds__(256) void pack_w(
    const int* __restrict__ w32, int8_t* __restrict__ w8, long long n4)
{
    const long long stride = (long long)gridDim.x * 256;
    for (long long i = (long long)blockIdx.x * 256 + threadIdx.x; i < n4; i += stride) {
        int4 v = ((const int4*)w32)[i];
        ((int*)w8)[i] = (v.x & 255) | ((v.y & 255) << 8) | ((v.z & 255) << 16) | ((v.w & 255) << 24);
    }
}

// ---------------- int8 GEMM, 2-phase, dbuf 48KB -> 2 blocks/CU ----------------
// BM=256, BN=128, BK=64B. 4 waves (2m x 2n), wave tile 128x64 = 8x4 frags of
// 16x16x64 -> 32 MFMA + 12 ds_read_b128 per wave per K-tile (ratio 2.67).
// Grid (M/256)*(N/128) = 768 = 3 blocks/CU sequential; __launch_bounds__(256,2)
// + 48KB LDS -> 2 INDEPENDENT blocks/CU resident = 2 staggered waves/SIMD:
// wave A's MFMA cluster overlaps wave B's ds_reads/barriers (m114).
// LDS: two 64B logical rows per 128B phys row, XOR swizzle x ^= (R&7)<<4
// (R2 counter-verified conflict-free); linear dest via global_load_lds +
// inverse-swizzled per-lane global src (rule #21).
// Dbuf ledger (distance 2, stage-at-end): prologue stages T0,T1 (12 loads out).
// Iter kt boundary: vmcnt(6) retires tile kt's 6, keeps kt+1's in flight;
// barrier publishes buf[kt&1]. Reads happen in phases; after the FINAL barrier
// (all waves provably done reading buf[kt&1]) stage tile kt+2 into buf[kt&1].
// Last boundary vmcnt(0).
__global__ __launch_bounds__(256, 2) void gemm_i8(
    const int8_t* __restrict__ xq, const int8_t* __restrict__ w,
    const float* __restrict__ sx, const float* __restrict__ scale,
    const float* __restrict__ bias, float* __restrict__ out,
    int M, int N, int K)
{
    __shared__ __align__(16) uint8_t lds[2][24576];   // [buf][A 16KB | B 8KB] = 48KB
    const int tid  = threadIdx.x;
    const int lane = tid & 63;
    const int wv   = tid >> 6;
    const int wr   = wv >> 1, wc = wv & 1;

    // bijective XCD swizzle (m204); nwg=768 -> %8==0
    const int nwg = gridDim.x;
    const int q8 = nwg >> 3, r8 = nwg & 7;
    const int xcd = blockIdx.x & 7, idx8 = blockIdx.x >> 3;
    const int wg = (xcd < r8 ? xcd * (q8 + 1) : r8 * (q8 + 1) + (xcd - r8) * q8) + idx8;

    const int NBM = M >> 8;
    const int bm = wg % NBM;
    const int bn = wg / NBM;       // col-panel-major: B panel (512KB) L2-resident
    const int brow = bm << 8, bcol = bn << 7;

    // staging sources (inverse-swizzled): chunk li covers phys bytes li*16..+15;
    // phys row R=li>>3 (128B), x=(li&7)<<4; logical r=(R<<1)|((x^swz)>>6), c=(x^swz)&63.
    const int8_t* srcA[4];
    const int8_t* srcB[2];
    #pragma unroll
    for (int e = 0; e < 4; ++e) {
        int li = e * 256 + tid;
        int R  = li >> 3;
        int x  = ((li & 7) << 4) ^ ((R & 7) << 4);
        srcA[e] = xq + (size_t)(brow + ((R << 1) | (x >> 6))) * K + (x & 63);
    }
    #pragma unroll
    for (int e = 0; e < 2; ++e) {
        int li = e * 256 + tid;
        int R  = li >> 3;
        int x  = ((li & 7) << 4) ^ ((R & 7) << 4);
        srcB[e] = w + (size_t)(bcol + ((R << 1) | (x >> 6))) * K + (x & 63);
    }

    // fragment LDS byte offsets (verified R2 formula)
    int offA[8], offB[4];
    #pragma unroll
    for (int m = 0; m < 8; ++m) {
        int r  = wr * 128 + m * 16 + (lane & 15);
        int R  = r >> 1;
        int x  = (((r & 1) << 6) | (lane & 48)) ^ ((R & 7) << 4);
        offA[m] = R * 128 + x;
    }
    #pragma unroll
    for (int n = 0; n < 4; ++n) {
        int r  = wc * 64 + n * 16 + (lane & 15);
        int R  = r >> 1;
        int x  = (((r & 1) << 6) | (lane & 48)) ^ ((R & 7) << 4);
        offB[n] = 16384 + R * 128 + x;
    }

    i32x4 acc[8][4] = {};

    auto stage = [&](int buf, int kt) {
        const size_t ko = (size_t)kt << 6;
        #pragma unroll
        for (int e = 0; e < 4; ++e)
            gload16(srcA[e] + ko, &lds[buf][e * 4096 + wv * 1024]);
        #pragma unroll
        for (int e = 0; e < 2; ++e)
            gload16(srcB[e] + ko, &lds[buf][16384 + e * 4096 + wv * 1024]);
    };

    const int NT = K >> 6;     // 64
    stage(0, 0);
    if (NT > 1) stage(1, 1);
    for (int kt = 0; kt < NT; ++kt) {
        if (kt < NT - 1) { VMCNT(6); } else { VMCNT(0); }
        BARRIER();                               // buf[kt&1] fully staged, visible
        const uint8_t* buf = lds[kt & 1];

        i32x4 av0[4], av1[4], bv[4];
        // ---- phase 0: read av(m0..3)+bv, MFMA m0..3 ----
        #pragma unroll
        for (int m = 0; m < 4; ++m) av0[m] = *(const i32x4*)(buf + offA[m]);
        #pragma unroll
        for (int n = 0; n < 4; ++n) bv[n] = *(const i32x4*)(buf + offB[n]);
        BARRIER();
        __builtin_amdgcn_s_setprio(1);
        #pragma unroll
        for (int m = 0; m < 4; ++m)
            #pragma unroll
            for (int n = 0; n < 4; ++n)
                acc[m][n] = __builtin_amdgcn_mfma_i32_16x16x64_i8(av0[m], bv[n], acc[m][n], 0, 0, 0);
        __builtin_amdgcn_s_setprio(0);
        // ---- phase 1: read av(m4..7), MFMA m4..7 ----
        #pragma unroll
        for (int m = 0; m < 4; ++m) av1[m] = *(const i32x4*)(buf + offA[4 + m]);
        BARRIER();
        __builtin_amdgcn_s_setprio(1);
        #pragma unroll
        for (int m = 0; m < 4; ++m)
            #pragma unroll
            for (int n = 0; n < 4; ++n)
                acc[4 + m][n] = __builtin_amdgcn_mfma_i32_16x16x64_i8(av1[m], bv[n], acc[4 + m][n], 0, 0, 0);
        __builtin_amdgcn_s_setprio(0);
        BARRIER();                               // all waves done reading buf[kt&1]
        if (kt + 2 < NT) stage(kt & 1, kt + 2);  // reuse the buffer just drained
    }

    // epilogue: out = acc * sx[row] * scale[col] + bias[col]
    const int orow = brow + wr * 128;
    const int ocol = bcol + wc * 64;
    float sxv[8][4];
    #pragma unroll
    for (int m = 0; m < 8; ++m)
        #pragma unroll
        for (int j = 0; j < 4; ++j)
            sxv[m][j] = sx[orow + m * 16 + ((lane >> 4) << 2) + j];
    #pragma unroll
    for (int n = 0; n < 4; ++n) {
        const int col = ocol + n * 16 + (lane & 15);
        const float sc = scale[col];
        const float bi = bias[col];
        #pragma unroll
        for (int m = 0; m < 8; ++m) {
            const int rb = orow + m * 16 + ((lane >> 4) << 2);
            #pragma unroll
            for (int j = 0; j < 4; ++j)
                out[(size_t)(rb + j) * N + col] = (float)acc[m][n][j] * sxv[m][j] * sc + bi;
        }
    }
}

extern "C" void kernel_launch(void* const* d_in, const int* in_sizes, int n_in,
                              void* d_out, int out_size, void* d_ws, size_t ws_size,
                              hipStream_t stream) {
    const float* x     = (const float*)d_in[0];
    const int*   w32   = (const int*)d_in[1];     // int8 weight arrives as int32 (harness ABI)
    const float* scale = (const float*)d_in[2];
    const float* bias  = (const float*)d_in[3];
    float* out = (float*)d_out;

    const int N = in_sizes[2];           // 6144
    const int K = in_sizes[1] / N;       // 4096
    const int M = in_sizes[0] / K;       // 4096

    // ws layout: xq [M*K int8] | wq [N*K int8] | sx [M f32]
    int8_t* xqbuf = (int8_t*)d_ws;
    int8_t* wqbuf = (int8_t*)d_ws + (size_t)M * K;
    float*  sxbuf = (float*)((uint8_t*)d_ws + (size_t)M * K + (size_t)N * K);

    if (K == 4096)
        quant4096<<<M, 256, 0, stream>>>(x, xqbuf, sxbuf);
    else
        quant_any<<<M, 256, 0, stream>>>(x, xqbuf, sxbuf, K);

    pack_w<<<2048, 256, 0, stream>>>(w32, wqbuf, (long long)N * K / 4);

    const int nwg = (M / 256) * (N / 128);   // 16*48 = 768
    gemm_i8<<<nwg, 256, 0, stream>>>(xqbuf, wqbuf, sxbuf, scale, bias, out, M, N, K);
}